// Round 11
// baseline (345.413 us; speedup 1.0000x reference)
//
#include <hip/hip_runtime.h>
#include <hip/hip_bf16.h>
#include <math.h>

typedef __bf16 bf16;
typedef __bf16 bf16x4 __attribute__((ext_vector_type(4)));
typedef __bf16 bf16x8 __attribute__((ext_vector_type(8)));
typedef float f32x4 __attribute__((ext_vector_type(4)));
typedef long longx2 __attribute__((ext_vector_type(2)));

#define C_DIM 512
#define S_DIM 8192

__device__ __forceinline__ void async_ld16(const void* g, void* l) {
    __builtin_amdgcn_global_load_lds(
        (const __attribute__((address_space(1))) unsigned int*)g,
        (__attribute__((address_space(3))) unsigned int*)l, 16, 0, 0);
}

// f32 -> OCP e4m3 via HW cvt (gfx950: v_cvt_pk_fp8_f32 emits OCP format)
__device__ __forceinline__ unsigned char to_fp8(float v) {
    return (unsigned char)(__builtin_amdgcn_cvt_pk_fp8_f32(v, v, 0, false) & 0xFF);
}

// ---------------- Kernel 0: dtype detect (wave ballot) + aux zeroing -----
// flag[0] = dtype flag; flag[16] = slot counter; flag[64..320) = cnt[256]
__global__ void detect_kernel(const unsigned short* __restrict__ xu, int* __restrict__ flag) {
    int j = threadIdx.x;   // 64 threads
    for (int i = 16 + j; i < 320; i += 64) flag[i] = 0;   // zero counter + cnt[256]
    unsigned e = (xu[2 * j] >> 7) & 0xFF;
    unsigned long long m = __ballot(e >= 90 && e <= 140);
    if (j == 0) *flag = (__popcll(m) >= 48) ? 1 : 0;   // 1 = bf16, 0 = fp32
}

// ---------------- Kernel 0b: weights -> bf16 (only needed in fp32 mode) --
__global__ __launch_bounds__(256) void convert_kernel(const void* __restrict__ s0,
                                                      const void* __restrict__ s1,
                                                      const void* __restrict__ s2,
                                                      const void* __restrict__ s3,
                                                      bf16* __restrict__ dst,
                                                      const int* __restrict__ flag) {
    if (*flag) return;   // bf16 inputs: GEMMs read originals directly
    int y = blockIdx.y;
    const void* srcs[4] = {s0, s1, s2, s3};
    const void* src = srcs[y];
    int i = blockIdx.x * 256 + threadIdx.x;
    bf16* d = dst + (size_t)y * 262144;
    volatile const float* s = (volatile const float*)src;
    d[i] = (bf16)s[i];
}

// ------------- Kernel 1+2 fused: RMS norm + transpose -> hn[b][s][c] -----
// 32-token blocks, grid 512 -> 2 blocks/CU (8 waves).
__global__ __launch_bounds__(256, 2) void rmshn_kernel(const void* __restrict__ x,
                                                       const void* __restrict__ gamma,
                                                       bf16* __restrict__ hn,
                                                       const int* __restrict__ flag) {
    __shared__ unsigned short Xs[512][34];   // 34.8 KB
    __shared__ float red[8][32];
    __shared__ float rbuf[32];
    int f  = *flag;
    int b  = blockIdx.x >> 8;
    int s0 = (blockIdx.x & 255) * 32;
    int col32 = threadIdx.x & 31;
    int rowc  = threadIdx.x >> 5;   // 0..7
    float acc = 0.f;
    if (f) {
        const unsigned short* xp = (const unsigned short*)x + (size_t)b * C_DIM * S_DIM + s0 + col32;
#pragma unroll 8
        for (int it = 0; it < 64; ++it) {
            int c = it * 8 + rowc;
            unsigned short u = xp[(size_t)c * S_DIM];
            float v = __uint_as_float(((unsigned int)u) << 16);
            acc += v * v;
            Xs[c][col32] = u;
        }
    } else {
        const float* xp = (const float*)x + (size_t)b * C_DIM * S_DIM + s0 + col32;
#pragma unroll 8
        for (int it = 0; it < 64; ++it) {
            int c = it * 8 + rowc;
            float v = xp[(size_t)c * S_DIM];
            acc += v * v;
            bf16 h = (bf16)v;
            Xs[c][col32] = *(unsigned short*)&h;
        }
    }
    red[rowc][col32] = acc;
    __syncthreads();
    if (rowc == 0) {
        float t = 0.f;
#pragma unroll
        for (int r = 0; r < 8; ++r) t += red[r][col32];
        rbuf[col32] = 22.627416997969522f / fmaxf(sqrtf(t), 1e-12f);
    }
    __syncthreads();
    int col64 = threadIdx.x & 63;
    int row4  = threadIdx.x >> 6;   // 0..3
    bf16* hp = hn + ((size_t)b * S_DIM + s0) * C_DIM;
    for (int cq = 0; cq < 8; ++cq) {
        int c = cq * 64 + col64;
        float g = f ? (float)((const bf16*)gamma)[c] : ((const float*)gamma)[c];
#pragma unroll
        for (int i = 0; i < 8; ++i) {
            int s_l = row4 + i * 4;   // 0..31
            float v = __uint_as_float(((unsigned int)Xs[c][s_l]) << 16);
            hp[(size_t)s_l * C_DIM + c] = (bf16)(v * rbuf[s_l] * g);
        }
    }
}

// ------------- Kernel 3a: fused QKV GEMM --------------------------------
// m97-style global_load_lds staging. q/K computed with SWAPPED MFMA
// operands (mfma(W_frag, A_frag)): output register tile transposes so rg
// walks 4 consecutive CHANNELS for a fixed token -> all three outputs
// become packed u32 stores (48 dword stores/thread vs 144 mixed before).
// V stays unswapped (its contiguous byte axis is the token, in-thread).
__global__ __launch_bounds__(256, 2) void gemm_qkv_kernel(const bf16* __restrict__ A,
                                                          const bf16* __restrict__ Wqc,
                                                          const bf16* __restrict__ Wkc,
                                                          const bf16* __restrict__ Wvc,
                                                          const void* __restrict__ wqo,
                                                          const void* __restrict__ wko,
                                                          const void* __restrict__ wvo,
                                                          const void* __restrict__ bq,
                                                          const void* __restrict__ bk,
                                                          const void* __restrict__ bv,
                                                          unsigned char* __restrict__ oq,
                                                          unsigned char* __restrict__ ok,
                                                          unsigned char* __restrict__ ov,
                                                          const int* __restrict__ flag) {
    __shared__ bf16 As [128 * 32];   // 8 KB each, linear 64-B rows
    __shared__ bf16 Bqs[128 * 32];
    __shared__ bf16 Bks[128 * 32];
    __shared__ bf16 Bvs[128 * 32];
    int f  = *flag;
    const bf16* Wq = f ? (const bf16*)wqo : Wqc;
    const bf16* Wk = f ? (const bf16*)wko : Wkc;
    const bf16* Wv = f ? (const bf16*)wvo : Wvc;
    int m0 = blockIdx.x * 128;
    int n0 = blockIdx.y * 128;
    int tid  = threadIdx.x;
    int lane = tid & 63;
    int wave = tid >> 6;
    int wm = (wave & 1) * 64;
    int wn = (wave >> 1) * 64;
    int l15  = lane & 15;
    int quad = lane >> 4;
    int wrow = lane >> 2;          // 0..15: row within 16-row slab
    int wcol = (lane & 3) * 8;     // 0/8/16/24: element quarter

    f32x4 aq[4][4] = {}, ak[4][4] = {}, av[4][4] = {};
    for (int k0 = 0; k0 < C_DIM; k0 += 32) {
        __syncthreads();
#pragma unroll
        for (int j = 0; j < 2; ++j) {
            int rowb = (j * 4 + wave) * 16;
            async_ld16(&A [(size_t)(m0 + rowb + wrow) * C_DIM + k0 + wcol], &As [rowb * 32]);
            async_ld16(&Wq[(size_t)(n0 + rowb + wrow) * C_DIM + k0 + wcol], &Bqs[rowb * 32]);
            async_ld16(&Wk[(size_t)(n0 + rowb + wrow) * C_DIM + k0 + wcol], &Bks[rowb * 32]);
            async_ld16(&Wv[(size_t)(n0 + rowb + wrow) * C_DIM + k0 + wcol], &Bvs[rowb * 32]);
        }
        __syncthreads();   // drains vmcnt -> staged data visible
        bf16x8 af[4];
#pragma unroll
        for (int i = 0; i < 4; ++i)
            af[i] = *(bf16x8*)&As[(wm + i * 16 + l15) * 32 + quad * 8];
#pragma unroll
        for (int j = 0; j < 4; ++j) {
            int boff = (wn + j * 16 + l15) * 32 + quad * 8;
            bf16x8 b0 = *(bf16x8*)&Bqs[boff];
#pragma unroll
            for (int i = 0; i < 4; ++i)   // SWAPPED: rows=channels, cols=tokens
                aq[i][j] = __builtin_amdgcn_mfma_f32_16x16x32_bf16(b0, af[i], aq[i][j], 0, 0, 0);
            bf16x8 b1 = *(bf16x8*)&Bks[boff];
#pragma unroll
            for (int i = 0; i < 4; ++i)   // SWAPPED
                ak[i][j] = __builtin_amdgcn_mfma_f32_16x16x32_bf16(b1, af[i], ak[i][j], 0, 0, 0);
            bf16x8 b2 = *(bf16x8*)&Bvs[boff];
#pragma unroll
            for (int i = 0; i < 4; ++i)   // unswapped (token axis in-thread)
                av[i][j] = __builtin_amdgcn_mfma_f32_16x16x32_bf16(af[i], b2, av[i][j], 0, 0, 0);
        }
    }
#pragma unroll
    for (int j = 0; j < 4; ++j) {
        int nb = n0 + wn + j * 16 + quad * 4;   // channel base for swapped q/K (rg=0)
        float bq4[4], bk4[4];
#pragma unroll
        for (int rg = 0; rg < 4; ++rg) {
            bq4[rg] = f ? (float)((const bf16*)bq)[nb + rg] : ((const float*)bq)[nb + rg];
            bk4[rg] = f ? (float)((const bf16*)bk)[nb + rg] : ((const float*)bk)[nb + rg];
        }
        int nv = n0 + wn + j * 16 + l15;        // channel for V (unswapped)
        float bvv = f ? (float)((const bf16*)bv)[nv] : ((const float*)bv)[nv];
#pragma unroll
        for (int i = 0; i < 4; ++i) {
            int m_tok = m0 + wm + i * 16 + l15;  // token for q/K (swapped col axis)
            // q: token-major [m][n], 4 consecutive channels in-thread
            unsigned qpack = 0;
#pragma unroll
            for (int rg = 0; rg < 4; ++rg)
                qpack |= (unsigned)to_fp8(aq[i][j][rg] + bq4[rg]) << (8 * rg);
            *(unsigned*)&oq[(size_t)m_tok * C_DIM + nb] = qpack;
            // K: frag layout, n&7 contiguous; n>>3.. bits constant across rg
            unsigned kpack = 0;
#pragma unroll
            for (int rg = 0; rg < 4; ++rg)
                kpack |= (unsigned)to_fp8(ak[i][j][rg] + bk4[rg]) << (8 * rg);
            size_t ikb = (size_t)(m_tok >> 5) * 16384 +
                         (((size_t)(nb >> 6) * 4 + ((nb >> 3) & 3)) * 32 + (m_tok & 31)) * 16 +
                         ((nb >> 5) & 1) * 8 + (nb & 7);
            *(unsigned*)&ok[ikb] = kpack;
            // V: unswapped acc; key (token) is the contiguous byte axis
            int mb = m0 + wm + i * 16 + quad * 4;
            unsigned vpack = 0;
#pragma unroll
            for (int rg = 0; rg < 4; ++rg)
                vpack |= (unsigned)to_fp8(av[i][j][rg] + bvv) << (8 * rg);
            size_t iv = (size_t)(mb >> 5) * 16384 + ((size_t)(mb >> 3) & 3) * 4096 +
                        (((size_t)(nv >> 5) * 16 + (nv & 15)) * 2 + ((nv >> 4) & 1)) * 8 + (mb & 7);
            *(unsigned*)&ov[iv] = vpack;
        }
    }
}

// ------------- Kernel 3b: output GEMM  out = A.Wo + bias + resid ---------
// Packed epilogue: rg spans 4 consecutive s positions (m 4-aligned, no
// b/s boundary crossing) -> 8B bf16x4 / 16B float4 resid loads + stores.
__global__ __launch_bounds__(256, 2) void gemm_kernel(const bf16* __restrict__ A,
                                                      const bf16* __restrict__ Wc,
                                                      const void* __restrict__ wo_orig,
                                                      const void* __restrict__ bias,
                                                      const void* __restrict__ resid,
                                                      void* __restrict__ out,
                                                      const int* __restrict__ flag) {
    __shared__ bf16 As[128 * 32];
    __shared__ bf16 Bs[128 * 32];
    int f  = *flag;
    const bf16* W = f ? (const bf16*)wo_orig : Wc;
    int m0 = blockIdx.x * 128;
    int n0 = blockIdx.y * 128;
    int tid  = threadIdx.x;
    int lane = tid & 63;
    int wave = tid >> 6;
    int wm = (wave & 1) * 64;
    int wn = (wave >> 1) * 64;
    int l15  = lane & 15;
    int quad = lane >> 4;
    int wrow = lane >> 2;
    int wcol = (lane & 3) * 8;

    f32x4 acc[4][4] = {};
    for (int k0 = 0; k0 < C_DIM; k0 += 32) {
        __syncthreads();
#pragma unroll
        for (int j = 0; j < 2; ++j) {
            int rowb = (j * 4 + wave) * 16;
            async_ld16(&A[(size_t)(m0 + rowb + wrow) * C_DIM + k0 + wcol], &As[rowb * 32]);
            async_ld16(&W[(size_t)(n0 + rowb + wrow) * C_DIM + k0 + wcol], &Bs[rowb * 32]);
        }
        __syncthreads();
        bf16x8 af[4], bfr[4];
#pragma unroll
        for (int i = 0; i < 4; ++i)
            af[i] = *(bf16x8*)&As[(wm + i * 16 + l15) * 32 + quad * 8];
#pragma unroll
        for (int j = 0; j < 4; ++j)
            bfr[j] = *(bf16x8*)&Bs[(wn + j * 16 + l15) * 32 + quad * 8];
#pragma unroll
        for (int i = 0; i < 4; ++i)
#pragma unroll
            for (int j = 0; j < 4; ++j)
                acc[i][j] = __builtin_amdgcn_mfma_f32_16x16x32_bf16(af[i], bfr[j], acc[i][j], 0, 0, 0);
    }
    if (f) {
        bf16* op = (bf16*)out;
        const bf16* rp = (const bf16*)resid;
#pragma unroll
        for (int i = 0; i < 4; ++i)
#pragma unroll
            for (int j = 0; j < 4; ++j) {
                int m = m0 + wm + i * 16 + quad * 4;   // rg=0 token
                int n = n0 + wn + j * 16 + l15;
                float bv = (float)((const bf16*)bias)[n];
                int b = m >> 13, s = m & 8191;
                size_t idx = ((size_t)b * C_DIM + n) * S_DIM + s;
                bf16x4 rv = *(const bf16x4*)&rp[idx];
                bf16x4 o4;
#pragma unroll
                for (int rg = 0; rg < 4; ++rg)
                    o4[rg] = (bf16)(acc[i][j][rg] + bv + (float)rv[rg]);
                *(bf16x4*)&op[idx] = o4;
            }
    } else {
        float* op = (float*)out;
        const float* rp = (const float*)resid;
#pragma unroll
        for (int i = 0; i < 4; ++i)
#pragma unroll
            for (int j = 0; j < 4; ++j) {
                int m = m0 + wm + i * 16 + quad * 4;
                int n = n0 + wn + j * 16 + l15;
                float bv = ((const float*)bias)[n];
                int b = m >> 13, s = m & 8191;
                size_t idx = ((size_t)b * C_DIM + n) * S_DIM + s;
                float4 rv = *(const float4*)&rp[idx];
                float4 o4;
                o4.x = acc[i][j][0] + bv + rv.x;
                o4.y = acc[i][j][1] + bv + rv.y;
                o4.z = acc[i][j][2] + bv + rv.z;
                o4.w = acc[i][j][3] + bv + rv.w;
                *(float4*)&op[idx] = o4;
            }
    }
}

// ------------- Kernel 4a: balanced split flash attention -----------------
// r8/r10 best config (unchanged): 512 blocks x 72 chunks, paired-b128 K/V
// reads, XCD-chunked swizzle, s_setprio around MFMA clusters, 4-chain QK.
__global__ __launch_bounds__(256, 2) void attn_split_kernel(const unsigned char* __restrict__ q,
                                                            const unsigned char* __restrict__ k,
                                                            const unsigned char* __restrict__ vt,
                                                            bf16* __restrict__ part,
                                                            float* __restrict__ lsum,
                                                            int* __restrict__ counter,
                                                            int* __restrict__ cnt,
                                                            int* __restrict__ slist) {
    __shared__ unsigned char Ks[2][16384];   // 32 KB
    __shared__ unsigned char Vs[2][16384];   // 32 KB
    __shared__ unsigned char Ps[4][16 * 40]; // 2.5 KB
    __shared__ int slot_sh;
    int tid  = threadIdx.x;
    int lane = tid & 63;
    int wave = tid >> 6;
    int l15  = lane & 15;
    int quad = lane >> 4;

    // ---- XCD-chunked swizzle: consecutive virtual ids land on one XCD ----
    int bid = blockIdx.x;
    int vb  = (bid & 7) * 64 + (bid >> 3);   // 512 = 8 XCDs x 64 chunks, bijective
    int g0 = vb * 72;
    int b_ = (g0 >= 18432) ? 1 : 0;
    int r  = g0 - b_ * 18432;
    int f_ = 0;
    while (r >= 256 * (f_ + 1) * (f_ + 2)) ++f_;
    int L   = 32 * (f_ + 1);
    int rr  = r - 256 * f_ * (f_ + 1);
    int tif = rr / L;
    int cw  = rr - tif * L;

    // ---- Q fragments for current tile (16 K-steps over C=512) ----
    long qf[16];
    {
        int qbase = (f_ * 16 + tif) * 64 + wave * 16;
        const unsigned char* qp = q + (size_t)(b_ * S_DIM + qbase + l15) * C_DIM;
#pragma unroll
        for (int ks = 0; ks < 16; ++ks)
            qf[ks] = *(const long*)&qp[ks * 32 + quad * 8];
    }

    f32x4 oacc[32] = {};
    float l_i[4] = {0.f, 0.f, 0.f, 0.f};
    const float scale = 0.044194173824159216f;  // 1/sqrt(512)

    // prefetch chunk 0 into buffer 0 (wave-uniform LDS base + lane*16)
    {
        const unsigned char* ka = k  + ((size_t)(b_ * 256 + cw) << 14);
        const unsigned char* va = vt + ((size_t)(b_ * 256 + cw) << 14);
#pragma unroll
        for (int j = 0; j < 4; ++j) {
            int base = (j * 4 + wave) * 1024;
            async_ld16(ka + base + lane * 16, &Ks[0][base]);
            async_ld16(va + base + lane * 16, &Vs[0][base]);
        }
    }
    __syncthreads();

    for (int i = 0; i < 72; ++i) {
        int last = (i == 71);
        int nb = b_, nf = f_, nL = L, ntif = tif, ncw = cw + 1;
        int newtile = 0;
        if (ncw == L) {
            ncw = 0; newtile = 1; ntif = tif + 1;
            if (ntif == 16) {
                ntif = 0; nf = f_ + 1; nL = L + 32;
                if (nf == 8) { nf = 0; nL = 32; nb = b_ + 1; }
            }
        }
        if (last) { nb = b_; nf = f_; nL = L; ntif = tif; ncw = cw; newtile = 0; }

        // ---- prefetch next chunk into the other buffer ----
        {
            const unsigned char* ka = k  + ((size_t)(nb * 256 + ncw) << 14);
            const unsigned char* va = vt + ((size_t)(nb * 256 + ncw) << 14);
            unsigned char* kd = Ks[(i + 1) & 1];
            unsigned char* vd = Vs[(i + 1) & 1];
#pragma unroll
            for (int j = 0; j < 4; ++j) {
                int base = (j * 4 + wave) * 1024;
                async_ld16(ka + base + lane * 16, kd + base);
                async_ld16(va + base + lane * 16, vd + base);
            }
        }
        const unsigned char* kb = Ks[i & 1];
        const unsigned char* vb2 = Vs[i & 1];

        // S = q . k^T : paired b128 reads, 4 independent 8-deep chains
        f32x4 sa[2] = {}, sb[2] = {};
        __builtin_amdgcn_s_setprio(1);
#pragma unroll
        for (int pp = 0; pp < 4; ++pp) {
#pragma unroll
            for (int nt = 0; nt < 2; ++nt) {
                longx2 ka2 = *(const longx2*)&kb[(((pp * 4 + quad) * 32) + nt * 16 + l15) * 16];
                longx2 kb2 = *(const longx2*)&kb[((((pp + 4) * 4 + quad) * 32) + nt * 16 + l15) * 16];
                sa[nt] = __builtin_amdgcn_mfma_f32_16x16x32_fp8_fp8(qf[2 * pp],     ka2[0], sa[nt], 0, 0, 0);
                sb[nt] = __builtin_amdgcn_mfma_f32_16x16x32_fp8_fp8(qf[2 * pp + 8], kb2[0], sb[nt], 0, 0, 0);
                sa[nt] = __builtin_amdgcn_mfma_f32_16x16x32_fp8_fp8(qf[2 * pp + 1], ka2[1], sa[nt], 0, 0, 0);
                sb[nt] = __builtin_amdgcn_mfma_f32_16x16x32_fp8_fp8(qf[2 * pp + 9], kb2[1], sb[nt], 0, 0, 0);
            }
        }
        __builtin_amdgcn_s_setprio(0);
        // softmax-lite: raw exp (scores bounded), per-lane l accumulation
        float p0[4], p1[4];
#pragma unroll
        for (int rg = 0; rg < 4; ++rg) {
            p0[rg] = __expf((sa[0][rg] + sb[0][rg]) * scale);
            p1[rg] = __expf((sa[1][rg] + sb[1][rg]) * scale);
            l_i[rg] += p0[rg] + p1[rg];
        }
        // P (C layout) -> per-wave fp8 LDS scratch -> A layout (same-wave)
        unsigned char* pw = Ps[wave];
#pragma unroll
        for (int rg = 0; rg < 4; ++rg) {
            pw[(quad * 4 + rg) * 40 + l15] = to_fp8(p0[rg]);
            pw[(quad * 4 + rg) * 40 + 16 + l15] = to_fp8(p1[rg]);
        }
        long pf = *(const long*)&pw[l15 * 40 + quad * 8];
        // PV: paired b128 reads = 2 dn per load
        __builtin_amdgcn_s_setprio(1);
#pragma unroll
        for (int dnp = 0; dnp < 16; ++dnp) {
            longx2 vf = *(const longx2*)&vb2[quad * 4096 + (dnp * 16 + l15) * 16];
            oacc[2 * dnp]     = __builtin_amdgcn_mfma_f32_16x16x32_fp8_fp8(pf, vf[0], oacc[2 * dnp], 0, 0, 0);
            oacc[2 * dnp + 1] = __builtin_amdgcn_mfma_f32_16x16x32_fp8_fp8(pf, vf[1], oacc[2 * dnp + 1], 0, 0, 0);
        }
        __builtin_amdgcn_s_setprio(0);

        // ---- flush segment at tile boundary / end of span ----
        if (last || newtile) {
            int ord = b_ * 128 + f_ * 16 + tif;   // q-tile ordinal 0..255
            if (tid == 0) {
                int s = atomicAdd(counter, 1);
                int pos = atomicAdd(&cnt[ord], 1);
                slist[ord * 8 + pos] = s;
                slot_sh = s;
            }
            __syncthreads();
            int slot = slot_sh;
#pragma unroll
            for (int rg = 0; rg < 4; ++rg)
                for (int d = 1; d < 16; d <<= 1)
                    l_i[rg] += __shfl_xor(l_i[rg], d);
            float rinv[4];
#pragma unroll
            for (int rg = 0; rg < 4; ++rg) rinv[rg] = 1.f / l_i[rg];
            bf16* pp2 = part + ((size_t)slot * 64 + wave * 16) * C_DIM;
#pragma unroll
            for (int dn = 0; dn < 32; ++dn)
#pragma unroll
                for (int rg = 0; rg < 4; ++rg)
                    pp2[(size_t)(quad * 4 + rg) * C_DIM + dn * 16 + l15] =
                        (bf16)(oacc[dn][rg] * rinv[rg]);
            if (l15 == 0) {
#pragma unroll
                for (int rg = 0; rg < 4; ++rg)
                    lsum[slot * 64 + wave * 16 + quad * 4 + rg] = l_i[rg];
            }
            if (!last) {
#pragma unroll
                for (int dn = 0; dn < 32; ++dn) oacc[dn] = (f32x4){0.f, 0.f, 0.f, 0.f};
#pragma unroll
                for (int rg = 0; rg < 4; ++rg) l_i[rg] = 0.f;
                int nqbase = (nf * 16 + ntif) * 64 + wave * 16;
                const unsigned char* qp = q + (size_t)(nb * S_DIM + nqbase + l15) * C_DIM;
#pragma unroll
                for (int ks = 0; ks < 16; ++ks)
                    qf[ks] = *(const long*)&qp[ks * 32 + quad * 8];
            }
        }
        b_ = nb; f_ = nf; L = nL; tif = ntif; cw = ncw;
        __syncthreads();   // drains prefetch + all waves done with buffers
    }
}

// ------------- Kernel 4b: non-split fallback flash attention -------------
__global__ __launch_bounds__(256, 2) void attn_kernel(const unsigned char* __restrict__ q,
                                                      const unsigned char* __restrict__ k,
                                                      const unsigned char* __restrict__ vt,
                                                      bf16* __restrict__ ob) {
    __shared__ unsigned char Ks[2][16384];
    __shared__ unsigned char Vs[2][16384];
    __shared__ unsigned char Ps[4][16 * 40];
    int id = blockIdx.x;
    int b = id >> 7;
    int t = id & 127;
    int q0 = t * 64;
    int kc1 = ((t >> 4) + 1) << 10;
    int tid  = threadIdx.x;
    int lane = tid & 63;
    int wave = tid >> 6;
    int l15  = lane & 15;
    int quad = lane >> 4;
    int qbase = q0 + wave * 16;
    int nchunks = kc1 >> 5;

    long qf[16];
    const unsigned char* qp = q + (size_t)(b * S_DIM + qbase + l15) * C_DIM;
#pragma unroll
    for (int ks = 0; ks < 16; ++ks)
        qf[ks] = *(const long*)&qp[ks * 32 + quad * 8];

    f32x4 oacc[32] = {};
    float l_i[4] = {0.f, 0.f, 0.f, 0.f};
    const float scale = 0.044194173824159216f;

    const unsigned char* kbase = k  + ((size_t)(b * 256) << 14);
    const unsigned char* vbase = vt + ((size_t)(b * 256) << 14);

#pragma unroll
    for (int j = 0; j < 4; ++j) {
        int base = (j * 4 + wave) * 1024;
        async_ld16(kbase + base + lane * 16, &Ks[0][base]);
        async_ld16(vbase + base + lane * 16, &Vs[0][base]);
    }
    __syncthreads();

    for (int p = 0; p < nchunks; ++p) {
        int pn = (p + 1 < nchunks) ? (p + 1) : p;
        const unsigned char* ksub = kbase + ((size_t)pn << 14);
        const unsigned char* vsub = vbase + ((size_t)pn << 14);
        unsigned char* kd = Ks[(p + 1) & 1];
        unsigned char* vd = Vs[(p + 1) & 1];
#pragma unroll
        for (int j = 0; j < 4; ++j) {
            int base = (j * 4 + wave) * 1024;
            async_ld16(ksub + base + lane * 16, kd + base);
            async_ld16(vsub + base + lane * 16, vd + base);
        }
        const unsigned char* kb = Ks[p & 1];
        const unsigned char* vb = Vs[p & 1];
        f32x4 st[2] = {};
#pragma unroll
        for (int nt = 0; nt < 2; ++nt) {
#pragma unroll
            for (int pp = 0; pp < 8; ++pp) {
                longx2 kf = *(const longx2*)&kb[(((pp * 4 + quad) * 32) + nt * 16 + l15) * 16];
                st[nt] = __builtin_amdgcn_mfma_f32_16x16x32_fp8_fp8(qf[2 * pp], kf[0], st[nt], 0, 0, 0);
                st[nt] = __builtin_amdgcn_mfma_f32_16x16x32_fp8_fp8(qf[2 * pp + 1], kf[1], st[nt], 0, 0, 0);
            }
        }
        float p0[4], p1[4];
#pragma unroll
        for (int rg = 0; rg < 4; ++rg) {
            p0[rg] = __expf(st[0][rg] * scale);
            p1[rg] = __expf(st[1][rg] * scale);
            l_i[rg] += p0[rg] + p1[rg];
        }
        unsigned char* pw = Ps[wave];
#pragma unroll
        for (int rg = 0; rg < 4; ++rg) {
            pw[(quad * 4 + rg) * 40 + l15] = to_fp8(p0[rg]);
            pw[(quad * 4 + rg) * 40 + 16 + l15] = to_fp8(p1[rg]);
        }
        long pf = *(const long*)&pw[l15 * 40 + quad * 8];
#pragma unroll
        for (int dnp = 0; dnp < 16; ++dnp) {
            longx2 vf = *(const longx2*)&vb[quad * 4096 + (dnp * 16 + l15) * 16];
            oacc[2 * dnp]     = __builtin_amdgcn_mfma_f32_16x16x32_fp8_fp8(pf, vf[0], oacc[2 * dnp], 0, 0, 0);
            oacc[2 * dnp + 1] = __builtin_amdgcn_mfma_f32_16x16x32_fp8_fp8(pf, vf[1], oacc[2 * dnp + 1], 0, 0, 0);
        }
        __syncthreads();
    }
#pragma unroll
    for (int rg = 0; rg < 4; ++rg)
        for (int d = 1; d < 16; d <<= 1)
            l_i[rg] += __shfl_xor(l_i[rg], d);
    float rinv[4];
#pragma unroll
    for (int rg = 0; rg < 4; ++rg) rinv[rg] = 1.f / l_i[rg];
    bf16* op = ob + (size_t)(b * S_DIM + qbase) * C_DIM;
#pragma unroll
    for (int dn = 0; dn < 32; ++dn)
#pragma unroll
        for (int rg = 0; rg < 4; ++rg)
            op[(size_t)(quad * 4 + rg) * C_DIM + dn * 16 + l15] =
                (bf16)(oacc[dn][rg] * rinv[rg]);
}

// ------------- Kernel 5: split-K combine (slot-list weighted sum) --------
// grid 256 x 4: blockIdx.y selects a 128-channel quarter.
__global__ __launch_bounds__(256) void combine_kernel(const bf16* __restrict__ part,
                                                      const float* __restrict__ lsum,
                                                      bf16* __restrict__ ob,
                                                      const int* __restrict__ cnt,
                                                      const int* __restrict__ slist) {
    int id = blockIdx.x;            // q-tile ordinal 0..255
    int b  = id >> 7;
    int q0 = (id & 127) * 64;
    int U  = cnt[id];               // 1..~5 segments
    int qq = threadIdx.x >> 2;      // 0..63
    int cr = threadIdx.x & 3;       // 32-ch sub-segment
    int cbase = blockIdx.y * 128 + cr * 32;
    int sl[8];
    float w[8];
    float D = 0.f;
    for (int u = 0; u < U; ++u) {
        sl[u] = slist[id * 8 + u];
        w[u] = lsum[sl[u] * 64 + qq];
        D += w[u];
    }
    float Dinv = 1.f / D;
    for (int u = 0; u < U; ++u) w[u] *= Dinv;
    bf16* op = ob + (size_t)(b * S_DIM + q0 + qq) * C_DIM + cbase;
    for (int ch = 0; ch < 4; ++ch) {
        float acc[8] = {};
        for (int u = 0; u < U; ++u) {
            bf16x8 pv = *(const bf16x8*)&part[((size_t)sl[u] * 64 + qq) * C_DIM + cbase + ch * 8];
#pragma unroll
            for (int j = 0; j < 8; ++j) acc[j] += w[u] * (float)pv[j];
        }
        bf16x8 o8;
#pragma unroll
        for (int j = 0; j < 8; ++j) o8[j] = (bf16)acc[j];
        *(bf16x8*)&op[ch * 8] = o8;
    }
}

extern "C" void kernel_launch(void* const* d_in, const int* in_sizes, int n_in,
                              void* d_out, int out_size, void* d_ws, size_t ws_size,
                              hipStream_t stream) {
    const void* x     = d_in[0];
    const void* gamma = d_in[1];
    const void* wq    = d_in[2];
    const void* bq    = d_in[3];
    const void* wk    = d_in[4];
    const void* bk    = d_in[5];
    const void* wv    = d_in[6];
    const void* bv    = d_in[7];
    const void* wo    = d_in[8];
    const void* bo    = d_in[9];

    char* ws = (char*)d_ws;
    int*   flag    = (int*)ws;                 // [0]=flag, [16]=slot counter, [64..320)=cnt
    int*   counter = (int*)(ws + 64);
    int*   cntp    = (int*)(ws + 256);
    int*   slist   = (int*)(ws + 0x12000);     // 256 q-tiles x 8 slots (8 KB)
    bf16* wqb = (bf16*)(ws + 0x20000);   // 4 weights contiguous, 512 KB each
    bf16* wkb = (bf16*)(ws + 0xA0000);
    bf16* wvb = (bf16*)(ws + 0x120000);
    bf16* wob = (bf16*)(ws + 0x1A0000);
    float* lsum_buf = (float*)(ws + 0x240000);                  // <=768 slots x 64 f32
    bf16* hn  = (bf16*)(ws + 0x400000);                         // 16 MB
    unsigned char* qb  = (unsigned char*)(ws + 0x1400000);      // 8 MB (fp8)
    unsigned char* kb  = (unsigned char*)(ws + 0x1C00000);      // 8 MB
    unsigned char* vtb = (unsigned char*)(ws + 0x2400000);      // 8 MB
    bf16* ob  = (bf16*)(ws + 0x2C00000);                        // 16 MB
    bf16* part = (bf16*)(ws + 0x5400000);                       // <=768 slots x 64 x 512 bf16 (50.3 MB)

    const size_t ws_needed_split = 0x5400000ull + 768ull * 64 * 512 * 2;
    int split = (ws_size >= ws_needed_split) ? 1 : 0;

    hipLaunchKernelGGL(detect_kernel, dim3(1), dim3(64), 0, stream,
                       (const unsigned short*)x, flag);
    hipLaunchKernelGGL(convert_kernel, dim3(1024, 4), dim3(256), 0, stream,
                       wq, wk, wv, wo, wqb, flag);
    hipLaunchKernelGGL(rmshn_kernel, dim3(512), dim3(256), 0, stream, x, gamma, hn, flag);
    hipLaunchKernelGGL(gemm_qkv_kernel, dim3(128, 4), dim3(256), 0, stream,
                       hn, wqb, wkb, wvb, wq, wk, wv, bq, bk, bv, qb, kb, vtb, flag);
    if (split) {
        hipLaunchKernelGGL(attn_split_kernel, dim3(512), dim3(256), 0, stream,
                           qb, kb, vtb, part, lsum_buf, counter, cntp, slist);
        hipLaunchKernelGGL(combine_kernel, dim3(256, 4), dim3(256), 0, stream,
                           part, lsum_buf, ob, cntp, slist);
    } else {
        hipLaunchKernelGGL(attn_kernel, dim3(256), dim3(256), 0, stream, qb, kb, vtb, ob);
    }
    hipLaunchKernelGGL(gemm_kernel, dim3(128, 4), dim3(256), 0, stream, ob, wob, wo, bo, x, d_out, flag);
}